// Round 10
// baseline (398.938 us; speedup 1.0000x reference)
//
#include <hip/hip_runtime.h>

// Problem constants
#define NEXP   8
#define L1DIM  3072
#define BATCH  32768
#define SQCORR (127.0f / 128.0f)
#define CHUNK  256                    // floats per row per K-step
#define NCHUNK (L1DIM / CHUNK)        // 12

// Workspace layout (int units). Fixed per-expert segments; cursors padded.
#define CUR_STRIDE  16
#define WS_CURSORS  0                       // [8 * CUR_STRIDE]
#define WS_SORTED   (NEXP * CUR_STRIDE)     // [NEXP*BATCH]
#define NBLK_SORT   (BATCH / 256)           // 128
#define BLK_PER_E   (BATCH / 16)            // 2048
#define NBLK_MAIN   (NEXP * BLK_PER_E)      // 16384 (most early-exit)

__global__ void init_k(int* ws) {
    if (threadIdx.x < NEXP)
        ws[WS_CURSORS + threadIdx.x * CUR_STRIDE] = threadIdx.x * BATCH;
}

// Block-aggregated scatter into fixed expert segments.
__global__ void scatter_k(const int* __restrict__ routing, int* ws) {
    __shared__ int h[NEXP];
    __shared__ int base[NEXP];
    if (threadIdx.x < NEXP) h[threadIdx.x] = 0;
    __syncthreads();
    int i = blockIdx.x * 256 + threadIdx.x;
    int e = routing[i];
    int rank = atomicAdd(&h[e], 1);
    __syncthreads();
    if (threadIdx.x < NEXP)
        base[threadIdx.x] =
            atomicAdd(&ws[WS_CURSORS + threadIdx.x * CUR_STRIDE], h[threadIdx.x]);
    __syncthreads();
    ws[WS_SORTED + base[e] + rank] = i;
}

// async 16B global -> LDS copy (per-lane global src, wave-linear LDS dest)
__device__ __forceinline__ void lds_cp16(void* lds, const void* g) {
    __builtin_amdgcn_global_load_lds(
        (const __attribute__((address_space(1))) void*)g,
        (__attribute__((address_space(3))) void*)lds, 16, 0, 0);
}

// Main fused kernel — R6 base (barrier-free, wave-private LDS x pipeline)
// + REGISTER-DOUBLE-BUFFERED w1: chunk t issues wv(t+1); its 256 FMAs
// (512 cy) cover the w1 L2/L3 latency that every prior variant paid
// exposed, once per chunk, in every wave (the actual wall per the cycle
// audit: ~1500 cy exposed vs 512 cy issue per wave-chunk).
//
// Per-wave vmcnt FIFO (gll + global loads share one counter):
//   chunk t issue order: [guard vmcnt(24)] ds_read xv(t) | 16x wv(t+1) |
//                        8x gll x(t+2) | FMA(wv_cur(t))
//   At top of chunk t, outstanding = [wv(t):16, x(t+1):8] = 24
//     -> guard vmcnt(24) is a free invariant check; x(t) is position >=25
//        and was drained by chunk t-1's wv-consumption wait (vmcnt(24)).
//   FMA wait on wv(t) allows [wv(t+1):16, x(t+2):8] outstanding ->
//     compiler emits vmcnt(24..39): NEVER drains the x prefetch. No
//     cross-wave hazards: LDS partitions are wave-private (gll dest
//     base r0 = wid*4), reads complete in-wave before rewrite.
__global__ __launch_bounds__(256, 2) void moe_main_k(
        const float* __restrict__ x, const int* __restrict__ ws,
        const float* __restrict__ w1, const float* __restrict__ b1,
        const float* __restrict__ w2, const float* __restrict__ b2,
        const float* __restrict__ w3, const float* __restrict__ b3,
        float* __restrict__ out) {
    __shared__ float xs[3][16][CHUNK];    // 48 KB; wave w owns rows 4w..4w+3

    const int e   = blockIdx.x % NEXP;
    const int b16 = (blockIdx.x / NEXP) * 16;
    const int n   = ws[WS_CURSORS + e * CUR_STRIDE] - e * BATCH;  // count_e
    if (b16 >= n) return;

    const int tid  = threadIdx.x;
    const int wid  = tid >> 6;
    const int lane = tid & 63;
    const int r0   = wid * 4;
    const int loff = lane * 4;

    int rows[4];
    const float* xp[4];
    #pragma unroll
    for (int q = 0; q < 4; ++q) {
        int s = b16 + r0 + q;
        rows[q] = (s < n) ? ws[WS_SORTED + e * BATCH + s] : -1;
        int r = rows[q] < 0 ? 0 : rows[q];
        xp[q] = x + (size_t)r * L1DIM;
    }
    const float* w1e = w1 + (size_t)e * 16 * L1DIM + loff;

    auto issue_x = [&](int t) {
        const int b = t % 3;
        const int koff = t * CHUNK + loff;
        #pragma unroll
        for (int q = 0; q < 4; ++q)
            lds_cp16(&xs[b][r0 + q][loff], xp[q] + koff);
    };
    auto load_wv = [&](int t, float4* wv) {
        const float* wc = w1e + t * CHUNK;
        #pragma unroll
        for (int o = 0; o < 16; ++o)
            wv[o] = *(const float4*)(wc + (size_t)o * L1DIM);
    };
    auto read_xv = [&](int t, float4* xv) {
        const int b = t % 3;
        #pragma unroll
        for (int q = 0; q < 4; ++q)
            xv[q] = *(const float4*)&xs[b][r0 + q][loff];
    };

    float acc[64];
    #pragma unroll
    for (int k = 0; k < 64; ++k) acc[k] = 0.0f;

    auto do_fma = [&](const float4* xv, const float4* wv) {
        #pragma unroll
        for (int o = 0; o < 16; ++o) {
            #pragma unroll
            for (int q = 0; q < 4; ++q) {
                float a = acc[q * 16 + o];
                a = fmaf(xv[q].x, wv[o].x, a);
                a = fmaf(xv[q].y, wv[o].y, a);
                a = fmaf(xv[q].z, wv[o].z, a);
                a = fmaf(xv[q].w, wv[o].w, a);
                acc[q * 16 + o] = a;
            }
        }
    };

    float4 wvA[16], wvB[16];

    // prologue: FIFO = [x(0):8, x(1):8, wvA(0):16]
    issue_x(0);
    issue_x(1);
    load_wv(0, wvA);

    #pragma unroll 1
    for (int t = 0; t < NCHUNK; t += 2) {
        // ---- even chunk t: consume wvA, load wvB(t+1), gll x(t+2) ----
        {
            asm volatile("s_waitcnt vmcnt(24)" ::: "memory");  // x(t) in LDS
            __builtin_amdgcn_sched_barrier(0);
            float4 xv[4];
            read_xv(t, xv);
            load_wv(t + 1, wvB);                    // always valid: t+1 <= 11
            __builtin_amdgcn_sched_barrier(0);
            if (t + 2 < NCHUNK) issue_x(t + 2);
            __builtin_amdgcn_sched_barrier(0);
            do_fma(xv, wvA);
        }
        // ---- odd chunk t+1: consume wvB, load wvA(t+2), gll x(t+3) ----
        {
            asm volatile("s_waitcnt vmcnt(24)" ::: "memory");  // x(t+1) in LDS
            __builtin_amdgcn_sched_barrier(0);
            float4 xv[4];
            read_xv(t + 1, xv);
            if (t + 2 < NCHUNK) load_wv(t + 2, wvA);
            __builtin_amdgcn_sched_barrier(0);
            if (t + 3 < NCHUNK) issue_x(t + 3);
            __builtin_amdgcn_sched_barrier(0);
            do_fma(xv, wvB);
        }
    }

    // Reduce-scatter butterfly: lane l ends with total of idx l (q*16+o).
    #pragma unroll
    for (int s = 0; s < 6; ++s) {
        const int mask = 32 >> s;
        const bool hi = (lane & mask) != 0;
        #pragma unroll
        for (int k = 0; k < 32; ++k) {
            if (k >= mask) break;
            float give = hi ? acc[k] : acc[k + mask];
            float got  = __shfl_xor(give, mask, 64);
            float keep = hi ? acc[k + mask] : acc[k];
            acc[k] = keep + got;
        }
    }

    // Shuffle-only epilogue (no LDS, no barrier). lane = q*16 + j.
    const int q = lane >> 4;
    const int j = lane & 15;
    const int row = rows[q];

    float tq[16];
    #pragma unroll
    for (int i = 0; i < 16; ++i)
        tq[i] = __shfl(acc[0], (lane & 48) | i, 64);

    float l1x_out = tq[15] + b1[e * 16 + 15];

    float h1v[30];
    #pragma unroll
    for (int i = 0; i < 15; ++i) {
        float v = tq[i] + b1[e * 16 + i];
        float sq = v * v * SQCORR;
        h1v[i]      = fminf(fmaxf(sq, 0.0f), 1.0f);
        h1v[i + 15] = fminf(fmaxf(v,  0.0f), 1.0f);
    }

    float s0 = b2[e * 32 + j];
    float s1 = b2[e * 32 + 16 + j];
    const float* w2e = w2 + (size_t)e * 32 * 30;
    #pragma unroll
    for (int i = 0; i < 30; ++i) {
        s0 = fmaf(h1v[i], w2e[j * 30 + i], s0);
        s1 = fmaf(h1v[i], w2e[(16 + j) * 30 + i], s1);
    }
    s0 = fminf(fmaxf(s0, 0.0f), 1.0f);
    s1 = fminf(fmaxf(s1, 0.0f), 1.0f);

    float p = s0 * w3[e * 32 + j] + s1 * w3[e * 32 + 16 + j];
    #pragma unroll
    for (int m = 8; m >= 1; m >>= 1) p += __shfl_xor(p, m, 64);

    if (j == 0 && row >= 0) out[row] = p + b3[e] + l1x_out;
}

extern "C" void kernel_launch(void* const* d_in, const int* in_sizes, int n_in,
                              void* d_out, int out_size, void* d_ws, size_t ws_size,
                              hipStream_t stream) {
    const float* x       = (const float*)d_in[0];
    const int*   routing = (const int*)d_in[1];
    const float* w1      = (const float*)d_in[2];
    const float* b1      = (const float*)d_in[3];
    const float* w2      = (const float*)d_in[4];
    const float* b2      = (const float*)d_in[5];
    const float* w3      = (const float*)d_in[6];
    const float* b3      = (const float*)d_in[7];
    float* out = (float*)d_out;
    int*   ws  = (int*)d_ws;

    init_k<<<1, 64, 0, stream>>>(ws);
    scatter_k<<<NBLK_SORT, 256, 0, stream>>>(routing, ws);
    moe_main_k<<<NBLK_MAIN, 256, 0, stream>>>(x, ws, w1, b1, w2, b2, w3, b3, out);
}

// Round 11
// 260.952 us; speedup vs baseline: 1.5288x; 1.5288x over previous
//
#include <hip/hip_runtime.h>

// Problem constants
#define NEXP   8
#define L1DIM  3072
#define BATCH  32768
#define SQCORR (127.0f / 128.0f)
#define CHUNK  256                    // floats per row per K-step
#define NCHUNK (L1DIM / CHUNK)        // 12

// Workspace layout (int units). Fixed per-expert segments; cursors padded.
#define CUR_STRIDE  16
#define WS_CURSORS  0                       // [8 * CUR_STRIDE]
#define WS_SORTED   (NEXP * CUR_STRIDE)     // [NEXP*BATCH]
#define NBLK_SORT   (BATCH / 256)           // 128
#define BLK_PER_E   (BATCH / 16)            // 2048
#define NBLK_MAIN   (NEXP * BLK_PER_E)      // 16384 (most early-exit)

__global__ void init_k(int* ws) {
    if (threadIdx.x < NEXP)
        ws[WS_CURSORS + threadIdx.x * CUR_STRIDE] = threadIdx.x * BATCH;
}

// Block-aggregated scatter into fixed expert segments.
__global__ void scatter_k(const int* __restrict__ routing, int* ws) {
    __shared__ int h[NEXP];
    __shared__ int base[NEXP];
    if (threadIdx.x < NEXP) h[threadIdx.x] = 0;
    __syncthreads();
    int i = blockIdx.x * 256 + threadIdx.x;
    int e = routing[i];
    int rank = atomicAdd(&h[e], 1);
    __syncthreads();
    if (threadIdx.x < NEXP)
        base[threadIdx.x] =
            atomicAdd(&ws[WS_CURSORS + threadIdx.x * CUR_STRIDE], h[threadIdx.x]);
    __syncthreads();
    ws[WS_SORTED + base[e] + rank] = i;
}

// async 16B global -> LDS copy (per-lane global src, wave-linear LDS dest)
__device__ __forceinline__ void lds_cp16(void* lds, const void* g) {
    __builtin_amdgcn_global_load_lds(
        (const __attribute__((address_space(1))) void*)g,
        (__attribute__((address_space(3))) void*)lds, 16, 0, 0);
}

// ===== MEASUREMENT ROUND: kernel body is EXACTLY the R6 best-known =====
// (barrier-free 4-independent-wave structure, 3-deep gll x pipeline,
// same-chunk w1 loads). kernel_launch launches it TWICE (idempotent:
// reads ws/x/weights only, overwrites out with identical values) so
// (a) main's true dur = total - 137.8, and (b) two ~300us main dispatches
// enter the rocprof top-5, exposing FETCH/VALUBusy/Occupancy for the
// good structure for the first time.
__global__ __launch_bounds__(256, 3) void moe_main_k(
        const float* __restrict__ x, const int* __restrict__ ws,
        const float* __restrict__ w1, const float* __restrict__ b1,
        const float* __restrict__ w2, const float* __restrict__ b2,
        const float* __restrict__ w3, const float* __restrict__ b3,
        float* __restrict__ out) {
    __shared__ float xs[3][16][CHUNK];    // 48 KB; wave w owns rows 4w..4w+3
    __shared__ float tot[4][64];          // wave-private slices

    const int e   = blockIdx.x % NEXP;
    const int b16 = (blockIdx.x / NEXP) * 16;
    const int n   = ws[WS_CURSORS + e * CUR_STRIDE] - e * BATCH;  // count_e
    if (b16 >= n) return;

    const int tid  = threadIdx.x;
    const int wid  = tid >> 6;
    const int lane = tid & 63;
    const int r0   = wid * 4;
    const int loff = lane * 4;

    int rows[4];
    const float* xp[4];
    #pragma unroll
    for (int q = 0; q < 4; ++q) {
        int s = b16 + r0 + q;
        rows[q] = (s < n) ? ws[WS_SORTED + e * BATCH + s] : -1;
        int r = rows[q] < 0 ? 0 : rows[q];
        xp[q] = x + (size_t)r * L1DIM;
    }
    const float* w1e = w1 + (size_t)e * 16 * L1DIM;

    auto issue_x = [&](int t, int b) {
        const int koff = t * CHUNK + loff;
        #pragma unroll
        for (int q = 0; q < 4; ++q)
            lds_cp16(&xs[b][r0 + q][loff], xp[q] + koff);
    };

    float acc[64];
    #pragma unroll
    for (int k = 0; k < 64; ++k) acc[k] = 0.0f;

    // prologue: x(0), x(1) in flight
    issue_x(0, 0);
    issue_x(1, 1);

    #pragma unroll 1
    for (int t = 0; t < NCHUNK; ++t) {
        const int xb = t % 3;
        asm volatile("s_waitcnt vmcnt(4)" ::: "memory");

        float4 xv[4];
        #pragma unroll
        for (int q = 0; q < 4; ++q)
            xv[q] = *(const float4*)&xs[xb][r0 + q][loff];

        const float* wc = w1e + t * CHUNK + loff;
        float4 wv[16];
        #pragma unroll
        for (int o = 0; o < 16; ++o)
            wv[o] = *(const float4*)(wc + (size_t)o * L1DIM);

        __builtin_amdgcn_sched_barrier(0);
        if (t + 2 < NCHUNK) issue_x(t + 2, (t + 2) % 3);
        __builtin_amdgcn_sched_barrier(0);

        #pragma unroll
        for (int o = 0; o < 16; ++o) {
            #pragma unroll
            for (int q = 0; q < 4; ++q) {
                float s = acc[q * 16 + o];
                s = fmaf(xv[q].x, wv[o].x, s);
                s = fmaf(xv[q].y, wv[o].y, s);
                s = fmaf(xv[q].z, wv[o].z, s);
                s = fmaf(xv[q].w, wv[o].w, s);
                acc[q * 16 + o] = s;
            }
        }
    }

    // Reduce-scatter butterfly over 64 lanes: lane l ends with total of idx l.
    #pragma unroll
    for (int s = 0; s < 6; ++s) {
        const int mask = 32 >> s;
        const bool hi = (lane & mask) != 0;
        #pragma unroll
        for (int k = 0; k < 32; ++k) {
            if (k >= mask) break;
            float give = hi ? acc[k] : acc[k + mask];
            float got  = __shfl_xor(give, mask, 64);
            float keep = hi ? acc[k + mask] : acc[k];
            acc[k] = keep + got;
        }
    }

    tot[wid][lane] = acc[0];
    __syncthreads();   // single barrier: orders the wave-private LDS totals

    // Epilogue: 16 lanes per row. lane = q*16 + j
    const int q = lane >> 4;
    const int j = lane & 15;
    const int row = rows[q];

    const float* tq = &tot[wid][q * 16];
    float l1x_out = tq[15] + b1[e * 16 + 15];

    float h1v[30];
    #pragma unroll
    for (int i = 0; i < 15; ++i) {
        float t = tq[i] + b1[e * 16 + i];
        float sq = t * t * SQCORR;
        h1v[i]      = fminf(fmaxf(sq, 0.0f), 1.0f);
        h1v[i + 15] = fminf(fmaxf(t,  0.0f), 1.0f);
    }

    float s0 = b2[e * 32 + j];
    float s1 = b2[e * 32 + 16 + j];
    const float* w2e = w2 + (size_t)e * 32 * 30;
    #pragma unroll
    for (int i = 0; i < 30; ++i) {
        s0 = fmaf(h1v[i], w2e[j * 30 + i], s0);
        s1 = fmaf(h1v[i], w2e[(16 + j) * 30 + i], s1);
    }
    s0 = fminf(fmaxf(s0, 0.0f), 1.0f);
    s1 = fminf(fmaxf(s1, 0.0f), 1.0f);

    float p = s0 * w3[e * 32 + j] + s1 * w3[e * 32 + 16 + j];
    #pragma unroll
    for (int m = 8; m >= 1; m >>= 1) p += __shfl_xor(p, m, 64);

    if (j == 0 && row >= 0) out[row] = p + b3[e] + l1x_out;
}

extern "C" void kernel_launch(void* const* d_in, const int* in_sizes, int n_in,
                              void* d_out, int out_size, void* d_ws, size_t ws_size,
                              hipStream_t stream) {
    const float* x       = (const float*)d_in[0];
    const int*   routing = (const int*)d_in[1];
    const float* w1      = (const float*)d_in[2];
    const float* b1      = (const float*)d_in[3];
    const float* w2      = (const float*)d_in[4];
    const float* b2      = (const float*)d_in[5];
    const float* w3      = (const float*)d_in[6];
    const float* b3      = (const float*)d_in[7];
    float* out = (float*)d_out;
    int*   ws  = (int*)d_ws;

    init_k<<<1, 64, 0, stream>>>(ws);
    scatter_k<<<NBLK_SORT, 256, 0, stream>>>(routing, ws);
    // Double launch (idempotent): main dur = total - 137.8us; both mains
    // surface in the rocprof top-5 with full counters.
    moe_main_k<<<NBLK_MAIN, 256, 0, stream>>>(x, ws, w1, b1, w2, b2, w3, b3, out);
    moe_main_k<<<NBLK_MAIN, 256, 0, stream>>>(x, ws, w1, b1, w2, b2, w3, b3, out);
}

// Round 12
// 112.038 us; speedup vs baseline: 3.5607x; 2.3291x over previous
//
#include <hip/hip_runtime.h>

// Problem constants
#define NEXP   8
#define L1DIM  3072
#define BATCH  32768
#define SQCORR (127.0f / 128.0f)
#define CHUNK  256                    // floats per row per K-step
#define NCHUNK (L1DIM / CHUNK)        // 12

// Workspace layout (int units). Fixed per-expert segments; cursors padded.
#define CUR_STRIDE  16
#define WS_CURSORS  0                       // [8 * CUR_STRIDE]
#define WS_SORTED   (NEXP * CUR_STRIDE)     // [NEXP*BATCH]
#define NBLK_SORT   (BATCH / 256)           // 128
#define BLK_PER_E   (BATCH / 16)            // 2048
#define NBLK_MAIN   (NEXP * BLK_PER_E)      // 16384 (most early-exit)

__global__ void init_k(int* ws) {
    if (threadIdx.x < NEXP)
        ws[WS_CURSORS + threadIdx.x * CUR_STRIDE] = threadIdx.x * BATCH;
}

// Block-aggregated scatter into fixed expert segments.
__global__ void scatter_k(const int* __restrict__ routing, int* ws) {
    __shared__ int h[NEXP];
    __shared__ int base[NEXP];
    if (threadIdx.x < NEXP) h[threadIdx.x] = 0;
    __syncthreads();
    int i = blockIdx.x * 256 + threadIdx.x;
    int e = routing[i];
    int rank = atomicAdd(&h[e], 1);
    __syncthreads();
    if (threadIdx.x < NEXP)
        base[threadIdx.x] =
            atomicAdd(&ws[WS_CURSORS + threadIdx.x * CUR_STRIDE], h[threadIdx.x]);
    __syncthreads();
    ws[WS_SORTED + base[e] + rank] = i;
}

// async 16B global -> LDS copy (per-lane global src, wave-linear LDS dest)
__device__ __forceinline__ void lds_cp16(void* lds, const void* g) {
    __builtin_amdgcn_global_load_lds(
        (const __attribute__((address_space(1))) void*)g,
        (__attribute__((address_space(3))) void*)lds, 16, 0, 0);
}

// Main fused kernel — O-SPLIT waves to kill the per-CU VMEM-pipe wall.
// R11 measurement: main = 123us vs 20.5us VALU floor / ~40us HBM floor.
// Audit: R6 issued 80 x 1KB VMEM instrs per block-chunk (each wave read
// ALL 16 w1 vectors: 4x redundancy -> 1.6GB of w1 through every CU's
// L1/TA pipe at ~8+ cy per instruction ~= 98us: the observed wall).
// Fix: wave w computes outputs [4w,4w+4) for ALL 16 block rows:
//   - wv loads: 16 per block-chunk (was 64); w1 traffic 1.6GB -> 402MB
//   - staging unchanged: wave stages its own 4 rows (4 gll/chunk)
//   - acc stays 64 regs/lane: acc[r*4+oo], r=0..15 block-row, oo=0..3
//   - cross-wave LDS reads => one s_barrier per chunk, preceded by
//     vmcnt(4): per-wave FIFO at that point = [x(t):4, x(t+1):4]
//     (chunk t-1's wv-consume wait vmcnt(4) already drained x(t-1) and
//     older) -> keeps x(t+1) in flight, guarantees own x(t) in LDS;
//     barrier then makes all waves' x(t) visible block-wide.
// Per block-chunk VMEM: 16 wv + 16 gll = 32 instrs (2.5x fewer).
__global__ __launch_bounds__(256, 2) void moe_main_k(
        const float* __restrict__ x, const int* __restrict__ ws,
        const float* __restrict__ w1, const float* __restrict__ b1,
        const float* __restrict__ w2, const float* __restrict__ b2,
        const float* __restrict__ w3, const float* __restrict__ b3,
        float* __restrict__ out) {
    __shared__ float xs[3][16][CHUNK];    // 48 KB
    __shared__ float tot[4][64];

    const int e   = blockIdx.x % NEXP;
    const int b16 = (blockIdx.x / NEXP) * 16;
    const int n   = ws[WS_CURSORS + e * CUR_STRIDE] - e * BATCH;  // count_e
    if (b16 >= n) return;    // uniform: all 4 waves exit before any barrier

    const int tid  = threadIdx.x;
    const int wid  = tid >> 6;
    const int lane = tid & 63;
    const int r0   = wid * 4;             // rows this wave STAGES
    const int loff = lane * 4;

    int rows[4];
    const float* xp[4];
    #pragma unroll
    for (int q = 0; q < 4; ++q) {
        int s = b16 + r0 + q;
        rows[q] = (s < n) ? ws[WS_SORTED + e * BATCH + s] : -1;
        int r = rows[q] < 0 ? 0 : rows[q];
        xp[q] = x + (size_t)r * L1DIM;
    }
    // this wave's 4 output rows of w1[e]: o = wid*4 + oo
    const float* w1e = w1 + ((size_t)e * 16 + wid * 4) * L1DIM + loff;

    auto issue_x = [&](int t) {
        const int b = t % 3;
        const int koff = t * CHUNK + loff;
        #pragma unroll
        for (int q = 0; q < 4; ++q)
            lds_cp16(&xs[b][r0 + q][loff], xp[q] + koff);
    };

    float acc[64];                        // acc[r*4 + oo]
    #pragma unroll
    for (int k = 0; k < 64; ++k) acc[k] = 0.0f;

    issue_x(0);
    issue_x(1);

    #pragma unroll 1
    for (int t = 0; t < NCHUNK; ++t) {
        const int xb = t % 3;
        // own x(t) drained (keep x(t+1) in flight), then block-wide visible
        asm volatile("s_waitcnt vmcnt(4)" ::: "memory");
        __builtin_amdgcn_s_barrier();
        __builtin_amdgcn_sched_barrier(0);

        // this wave's 4 w1 vectors for chunk t (only o-slice it owns)
        float4 wv[4];
        #pragma unroll
        for (int oo = 0; oo < 4; ++oo)
            wv[oo] = *(const float4*)(w1e + t * CHUNK + (size_t)oo * L1DIM);

        __builtin_amdgcn_sched_barrier(0);
        if (t + 2 < NCHUNK) issue_x(t + 2);
        __builtin_amdgcn_sched_barrier(0);

        // all 16 block rows x this wave's 4 outputs
        #pragma unroll
        for (int rg = 0; rg < 4; ++rg) {
            float4 xv[4];
            #pragma unroll
            for (int rr = 0; rr < 4; ++rr)
                xv[rr] = *(const float4*)&xs[xb][rg * 4 + rr][loff];
            #pragma unroll
            for (int oo = 0; oo < 4; ++oo) {
                #pragma unroll
                for (int rr = 0; rr < 4; ++rr) {
                    const int v = (rg * 4 + rr) * 4 + oo;
                    float a = acc[v];
                    a = fmaf(xv[rr].x, wv[oo].x, a);
                    a = fmaf(xv[rr].y, wv[oo].y, a);
                    a = fmaf(xv[rr].z, wv[oo].z, a);
                    a = fmaf(xv[rr].w, wv[oo].w, a);
                    acc[v] = a;
                }
            }
        }
    }

    // Reduce-scatter butterfly: lane l ends with total of value idx l,
    // where idx v = block_row(v>>2)*4 + oo; this wave's o = wid*4+oo.
    #pragma unroll
    for (int s = 0; s < 6; ++s) {
        const int mask = 32 >> s;
        const bool hi = (lane & mask) != 0;
        #pragma unroll
        for (int k = 0; k < 32; ++k) {
            if (k >= mask) break;
            float give = hi ? acc[k] : acc[k + mask];
            float got  = __shfl_xor(give, mask, 64);
            float keep = hi ? acc[k + mask] : acc[k];
            acc[k] = keep + got;
        }
    }

    tot[wid][lane] = acc[0];   // tot[w][R*4+oo] = out (R, o=w*4+oo)
    __syncthreads();

    // Epilogue: wave wid handles block rows wid*4+q (== its rows[q]).
    const int q = lane >> 4;
    const int j = lane & 15;
    const int row = rows[q];
    const int rl  = wid * 4 + q;          // block-row index

    float tq[16];
    #pragma unroll
    for (int i = 0; i < 16; ++i)
        tq[i] = tot[i >> 2][rl * 4 + (i & 3)];

    float l1x_out = tq[15] + b1[e * 16 + 15];

    float h1v[30];
    #pragma unroll
    for (int i = 0; i < 15; ++i) {
        float v = tq[i] + b1[e * 16 + i];
        float sq = v * v * SQCORR;
        h1v[i]      = fminf(fmaxf(sq, 0.0f), 1.0f);
        h1v[i + 15] = fminf(fmaxf(v,  0.0f), 1.0f);
    }

    float s0 = b2[e * 32 + j];
    float s1 = b2[e * 32 + 16 + j];
    const float* w2e = w2 + (size_t)e * 32 * 30;
    #pragma unroll
    for (int i = 0; i < 30; ++i) {
        s0 = fmaf(h1v[i], w2e[j * 30 + i], s0);
        s1 = fmaf(h1v[i], w2e[(16 + j) * 30 + i], s1);
    }
    s0 = fminf(fmaxf(s0, 0.0f), 1.0f);
    s1 = fminf(fmaxf(s1, 0.0f), 1.0f);

    float p = s0 * w3[e * 32 + j] + s1 * w3[e * 32 + 16 + j];
    #pragma unroll
    for (int m = 8; m >= 1; m >>= 1) p += __shfl_xor(p, m, 64);

    if (j == 0 && row >= 0) out[row] = p + b3[e] + l1x_out;
}

extern "C" void kernel_launch(void* const* d_in, const int* in_sizes, int n_in,
                              void* d_out, int out_size, void* d_ws, size_t ws_size,
                              hipStream_t stream) {
    const float* x       = (const float*)d_in[0];
    const int*   routing = (const int*)d_in[1];
    const float* w1      = (const float*)d_in[2];
    const float* b1      = (const float*)d_in[3];
    const float* w2      = (const float*)d_in[4];
    const float* b2      = (const float*)d_in[5];
    const float* w3      = (const float*)d_in[6];
    const float* b3      = (const float*)d_in[7];
    float* out = (float*)d_out;
    int*   ws  = (int*)d_ws;

    init_k<<<1, 64, 0, stream>>>(ws);
    scatter_k<<<NBLK_SORT, 256, 0, stream>>>(routing, ws);
    moe_main_k<<<NBLK_MAIN, 256, 0, stream>>>(x, ws, w1, b1, w2, b2, w3, b3, out);
}